// Round 5
// baseline (153.802 us; speedup 1.0000x reference)
//
#include <hip/hip_runtime.h>

#define HH 256
#define WW 128
#define DD 256
#define HID 8
#define NBLK 32
#define UNR 4

typedef float v4f __attribute__((ext_vector_type(4)));

#define KEEP4(v) asm volatile("" : "+v"((v).x), "+v"((v).y), "+v"((v).z), "+v"((v).w))

__device__ __forceinline__ float rlane(float v, int l) {
    return __int_as_float(__builtin_amdgcn_readlane(__float_as_int(v), l));
}

__global__ __launch_bounds__(256, 3)   // VGPR cap 170: weights stay resident, 3 waves/SIMD
void lca_kernel(const float* __restrict__ x, const float* __restrict__ We,
                const float* __restrict__ be, const float* __restrict__ Wd,
                const float* __restrict__ bd, float* __restrict__ out) {
    const int bid  = blockIdx.x;
    const int pg   = bid >> 6;        // 0..31 : group of 4 adjacent patches
    const int nb   = bid & 63;        // 0..63 : sample block
    const int tid  = threadIdx.x;
    const int wave = tid >> 6;
    const int lane = tid & 63;
    const int p    = pg * 4 + wave;   // one wave per patch
    const int ph   = p >> 3, pw = p & 7;

    // lane owns d = 4*lane .. 4*lane+3 -> patch row i = lane>>2, col j = (lane&3)*4
    const int i = lane >> 2, j = (lane & 3) * 4;
    const int off0 = (ph * 16 + i) * WW + pw * 16 + j;

    // ---- weight preload into registers (once per block) ----
    v4f we4[HID];
#pragma unroll
    for (int h = 0; h < HID; ++h)
        we4[h] = *(const v4f*)(We + ((size_t)(p * HID + h)) * DD + lane * 4);
    float bev[HID];
#pragma unroll
    for (int h = 0; h < HID; ++h) bev[h] = be[p * HID + h];
    v4f wd4[4][2];
#pragma unroll
    for (int c = 0; c < 4; ++c) {
        const v4f* wp = (const v4f*)(Wd + ((size_t)(p * DD + lane * 4 + c)) * HID);
        wd4[c][0] = wp[0];
        wd4[c][1] = wp[1];
    }
    v4f bdv = *(const v4f*)(bd + p * DD + lane * 4);

#pragma unroll
    for (int h = 0; h < HID; ++h) KEEP4(we4[h]);
#pragma unroll
    for (int c = 0; c < 4; ++c) { KEEP4(wd4[c][0]); KEEP4(wd4[c][1]); }

    const bool b5 = (lane & 32) != 0;
    const bool b4 = (lane & 16) != 0;
    const bool b3 = (lane & 8)  != 0;

    const float* xp0 = x   + (size_t)(nb * NBLK) * (HH * WW) + off0;
    float*       op0 = out + (size_t)(nb * NBLK) * (HH * WW) + off0;

    auto compute_store = [&](v4f (&xv)[UNR], int nn) {
        // encode partials + reduce-scatter stage mask32 (keep 4 of 8)
        float a[UNR][4];
#pragma unroll
        for (int u = 0; u < UNR; ++u) {
            float z[HID];
#pragma unroll
            for (int h = 0; h < HID; ++h)
                z[h] = fmaf(we4[h].x, xv[u].x,
                       fmaf(we4[h].y, xv[u].y,
                       fmaf(we4[h].z, xv[u].z, we4[h].w * xv[u].w)));
#pragma unroll
            for (int c = 0; c < 4; ++c) {
                float send = b5 ? z[c]     : z[c + 4];
                float keep = b5 ? z[c + 4] : z[c];
                a[u][c] = keep + __shfl_xor(send, 32);
            }
        }
        // stage mask16 (keep 2 of 4)
        float bb[UNR][2];
#pragma unroll
        for (int u = 0; u < UNR; ++u) {
#pragma unroll
            for (int c = 0; c < 2; ++c) {
                float send = b4 ? a[u][c]     : a[u][c + 2];
                float keep = b4 ? a[u][c + 2] : a[u][c];
                bb[u][c] = keep + __shfl_xor(send, 16);
            }
        }
        // stage mask8 (keep 1 of 2); lane owns h = 4*b5 + 2*b4 + b3
        float s1[UNR];
#pragma unroll
        for (int u = 0; u < UNR; ++u) {
            float send = b3 ? bb[u][0] : bb[u][1];
            float keep = b3 ? bb[u][1] : bb[u][0];
            s1[u] = keep + __shfl_xor(send, 8);
        }
        // finish over lane bits 2:0 (butterfly, 3 stages)
#pragma unroll
        for (int m = 4; m >= 1; m >>= 1) {
#pragma unroll
            for (int u = 0; u < UNR; ++u)
                s1[u] += __shfl_xor(s1[u], m);
        }
        // broadcast via readlane (h lives at lane h*8) + decode + sigmoid + store
#pragma unroll
        for (int u = 0; u < UNR; ++u) {
            float zf[HID];
#pragma unroll
            for (int h = 0; h < HID; ++h)
                zf[h] = rlane(s1[u], h * 8) + bev[h];
            v4f o;
#pragma unroll
            for (int c = 0; c < 4; ++c) {
                float s = bdv[c];
#pragma unroll
                for (int h = 0; h < 4; ++h) s = fmaf(wd4[c][0][h], zf[h], s);
#pragma unroll
                for (int h = 0; h < 4; ++h) s = fmaf(wd4[c][1][h], zf[h + 4], s);
                o[c] = __builtin_amdgcn_rcpf(1.0f + __expf(-s));
            }
            *(v4f*)(op0 + (size_t)(nn + u) * (HH * WW)) = o;
        }
    };

    // software pipeline: prefetch next UNR samples while computing current
    v4f xv[UNR], xnx[UNR];
#pragma unroll
    for (int u = 0; u < UNR; ++u)
        xv[u] = *(const v4f*)(xp0 + (size_t)u * (HH * WW));

#pragma unroll 1
    for (int nn = 0; nn < NBLK - UNR; nn += UNR) {
#pragma unroll
        for (int u = 0; u < UNR; ++u)
            xnx[u] = *(const v4f*)(xp0 + (size_t)(nn + UNR + u) * (HH * WW));
        compute_store(xv, nn);
#pragma unroll
        for (int u = 0; u < UNR; ++u) xv[u] = xnx[u];
    }
    compute_store(xv, NBLK - UNR);
}

extern "C" void kernel_launch(void* const* d_in, const int* in_sizes, int n_in,
                              void* d_out, int out_size, void* d_ws, size_t ws_size,
                              hipStream_t stream) {
    const float* x  = (const float*)d_in[0];
    const float* We = (const float*)d_in[1];
    const float* be = (const float*)d_in[2];
    const float* Wd = (const float*)d_in[3];
    const float* bd = (const float*)d_in[4];
    float* out = (float*)d_out;

    const int n_total = in_sizes[0] / (HH * WW);            // 2048
    const int grid    = 32 * (n_total / NBLK);              // 32 * 64 = 2048
    lca_kernel<<<dim3(grid), dim3(256), 0, stream>>>(x, We, be, Wd, bd, out);
}

// Round 6
// 146.096 us; speedup vs baseline: 1.0527x; 1.0527x over previous
//
#include <hip/hip_runtime.h>

#define HH 256
#define WW 128
#define DD 256
#define HID 8
#define NBLK 32
#define UNR 2

typedef float v4f __attribute__((ext_vector_type(4)));

// Home a value in an AGPR (write once, volatile so it can't be sunk/duplicated)
#define AWR(dst, src) asm volatile("v_accvgpr_write_b32 %0, %1" : "=a"(dst) : "v"(src))
// Copy AGPR -> VGPR (non-volatile: CSE-able, 2cy, no memory traffic)
#define ARD(dst, src) asm("v_accvgpr_read_b32 %0, %1" : "=v"(dst) : "a"(src))

__device__ __forceinline__ float rlane(float v, int l) {
    return __int_as_float(__builtin_amdgcn_readlane(__float_as_int(v), l));
}

__global__ __launch_bounds__(256, 3)
void lca_kernel(const float* __restrict__ x, const float* __restrict__ We,
                const float* __restrict__ be, const float* __restrict__ Wd,
                const float* __restrict__ bd, float* __restrict__ out) {
    const int bid  = blockIdx.x;
    const int pg   = bid >> 6;        // 0..31 : group of 4 adjacent patches
    const int nb   = bid & 63;        // 0..63 : sample block
    const int tid  = threadIdx.x;
    const int wave = tid >> 6;
    const int lane = tid & 63;
    const int p    = pg * 4 + wave;   // one wave per patch
    const int ph   = p >> 3, pw = p & 7;

    // lane owns d = 4*lane .. 4*lane+3 -> patch row i = lane>>2, col j = (lane&3)*4
    const int i = lane >> 2, j = (lane & 3) * 4;
    const int off0 = (ph * 16 + i) * WW + pw * 16 + j;

    // ---- load weights once, home them in AGPRs ----
    float wea[HID][4];            // We[p][h][4l..4l+3]
#pragma unroll
    for (int h = 0; h < HID; ++h) {
        v4f t = *(const v4f*)(We + ((size_t)(p * HID + h)) * DD + lane * 4);
        AWR(wea[h][0], t.x); AWR(wea[h][1], t.y);
        AWR(wea[h][2], t.z); AWR(wea[h][3], t.w);
    }
    float wda[4][8];              // Wd[p][4l+c][h]
#pragma unroll
    for (int c = 0; c < 4; ++c) {
        const v4f* wp = (const v4f*)(Wd + ((size_t)(p * DD + lane * 4 + c)) * HID);
        v4f t0 = wp[0], t1 = wp[1];
        AWR(wda[c][0], t0.x); AWR(wda[c][1], t0.y);
        AWR(wda[c][2], t0.z); AWR(wda[c][3], t0.w);
        AWR(wda[c][4], t1.x); AWR(wda[c][5], t1.y);
        AWR(wda[c][6], t1.z); AWR(wda[c][7], t1.w);
    }
    float beva[HID];
#pragma unroll
    for (int h = 0; h < HID; ++h) { float t = be[p * HID + h]; AWR(beva[h], t); }
    float bdva[4];
    {
        v4f t = *(const v4f*)(bd + p * DD + lane * 4);
        AWR(bdva[0], t.x); AWR(bdva[1], t.y); AWR(bdva[2], t.z); AWR(bdva[3], t.w);
    }

    const bool b5 = (lane & 32) != 0;
    const bool b4 = (lane & 16) != 0;
    const bool b3 = (lane & 8)  != 0;

    const float* xp0 = x   + (size_t)(nb * NBLK) * (HH * WW) + off0;
    float*       op0 = out + (size_t)(nb * NBLK) * (HH * WW) + off0;

#pragma unroll 1
    for (int nn = 0; nn < NBLK; nn += UNR) {
        // load UNR samples' fragments
        v4f xv[UNR];
#pragma unroll
        for (int u = 0; u < UNR; ++u)
            xv[u] = *(const v4f*)(xp0 + (size_t)(nn + u) * (HH * WW));

        // fetch encode weights from AGPR (register copies, no memory)
        float we[HID][4];
#pragma unroll
        for (int h = 0; h < HID; ++h)
#pragma unroll
            for (int c = 0; c < 4; ++c) ARD(we[h][c], wea[h][c]);

        // encode partials + reduce-scatter stage mask32 (keep 4 of 8)
        float a[UNR][4];
#pragma unroll
        for (int u = 0; u < UNR; ++u) {
            float z[HID];
#pragma unroll
            for (int h = 0; h < HID; ++h)
                z[h] = fmaf(we[h][0], xv[u].x,
                       fmaf(we[h][1], xv[u].y,
                       fmaf(we[h][2], xv[u].z, we[h][3] * xv[u].w)));
#pragma unroll
            for (int c = 0; c < 4; ++c) {
                float send = b5 ? z[c]     : z[c + 4];
                float keep = b5 ? z[c + 4] : z[c];
                a[u][c] = keep + __shfl_xor(send, 32);
            }
        }
        // stage mask16 (keep 2 of 4)
        float bb[UNR][2];
#pragma unroll
        for (int u = 0; u < UNR; ++u) {
#pragma unroll
            for (int c = 0; c < 2; ++c) {
                float send = b4 ? a[u][c]     : a[u][c + 2];
                float keep = b4 ? a[u][c + 2] : a[u][c];
                bb[u][c] = keep + __shfl_xor(send, 16);
            }
        }
        // stage mask8 (keep 1 of 2); lane owns h = 4*b5 + 2*b4 + b3
        float s1[UNR];
#pragma unroll
        for (int u = 0; u < UNR; ++u) {
            float send = b3 ? bb[u][0] : bb[u][1];
            float keep = b3 ? bb[u][1] : bb[u][0];
            s1[u] = keep + __shfl_xor(send, 8);
        }
        // finish over lane bits 2:0 (butterfly, 3 stages)
#pragma unroll
        for (int m = 4; m >= 1; m >>= 1) {
#pragma unroll
            for (int u = 0; u < UNR; ++u)
                s1[u] += __shfl_xor(s1[u], m);
        }

        // fetch decode weights + biases from AGPR
        float wd[4][8];
#pragma unroll
        for (int c = 0; c < 4; ++c)
#pragma unroll
            for (int h = 0; h < HID; ++h) ARD(wd[c][h], wda[c][h]);
        float bev[HID];
#pragma unroll
        for (int h = 0; h < HID; ++h) ARD(bev[h], beva[h]);
        float bdv[4];
#pragma unroll
        for (int c = 0; c < 4; ++c) ARD(bdv[c], bdva[c]);

        // broadcast via readlane (h lives at lane h*8) + decode + sigmoid + store
#pragma unroll
        for (int u = 0; u < UNR; ++u) {
            float zf[HID];
#pragma unroll
            for (int h = 0; h < HID; ++h)
                zf[h] = rlane(s1[u], h * 8) + bev[h];
            v4f o;
#pragma unroll
            for (int c = 0; c < 4; ++c) {
                float s = bdv[c];
#pragma unroll
                for (int h = 0; h < HID; ++h) s = fmaf(wd[c][h], zf[h], s);
                o[c] = __builtin_amdgcn_rcpf(1.0f + __expf(-s));
            }
            *(v4f*)(op0 + (size_t)(nn + u) * (HH * WW)) = o;
        }
    }
}

extern "C" void kernel_launch(void* const* d_in, const int* in_sizes, int n_in,
                              void* d_out, int out_size, void* d_ws, size_t ws_size,
                              hipStream_t stream) {
    const float* x  = (const float*)d_in[0];
    const float* We = (const float*)d_in[1];
    const float* be = (const float*)d_in[2];
    const float* Wd = (const float*)d_in[3];
    const float* bd = (const float*)d_in[4];
    float* out = (float*)d_out;

    const int n_total = in_sizes[0] / (HH * WW);            // 2048
    const int grid    = 32 * (n_total / NBLK);              // 32 * 64 = 2048
    lca_kernel<<<dim3(grid), dim3(256), 0, stream>>>(x, We, be, Wd, bd, out);
}

// Round 7
// 125.782 us; speedup vs baseline: 1.2228x; 1.1615x over previous
//
#include <hip/hip_runtime.h>

#define HH 256
#define WW 128
#define DD 256
#define HID 8
#define G 16              // samples per block
#define PSTRIDE 264       // padded per-patch stride in floats (256 + 8)
#define IMG (HH * WW)     // 32768 floats per sample

typedef float v4f __attribute__((ext_vector_type(4)));

__device__ __forceinline__ float rlane(float v, int l) {
    return __int_as_float(__builtin_amdgcn_readlane(__float_as_int(v), l));
}

__global__ __launch_bounds__(512, 4)
void lca_kernel(const float* __restrict__ x, const float* __restrict__ We,
                const float* __restrict__ be, const float* __restrict__ Wd,
                const float* __restrict__ bd, float* __restrict__ out) {
    __shared__ float Xb[2][8 * PSTRIDE];   // staged input, patch-major, dbuf
    __shared__ float Ob[8 * PSTRIDE];      // staged output, patch-major

    const int bid = blockIdx.x;
    const int ph  = bid & 15;              // stripe (16 rows of the image)
    const int sg  = bid >> 4;              // sample group 0..127
    const int tid = threadIdx.x;
    const int w   = tid >> 6;              // wave index == patch pw within stripe
    const int l   = tid & 63;

    const int p = ph * 8 + w;              // global patch id for this wave

    // ---- stage mapping: thread t handles contiguous float4 at stripe offset 4t
    // global (row r_t, col c): r_t = t>>5, c = (4t)&127 -> patch pw_t = c>>4, jj_t = c&15
    const int r_t  = tid >> 5;
    const int pw_t = (tid >> 2) & 7;
    const int jj_t = (tid & 3) * 4;
    const int lds_stage = pw_t * PSTRIDE + r_t * 16 + jj_t;   // patch-major slot
    const int goff = tid * 4;                                  // contiguous offset

    // ---- weight preload (per wave, its patch) ----
    v4f we4[HID];
#pragma unroll
    for (int h = 0; h < HID; ++h)
        we4[h] = *(const v4f*)(We + ((size_t)(p * HID + h)) * DD + l * 4);
    float bev[HID];
#pragma unroll
    for (int h = 0; h < HID; ++h) bev[h] = be[p * HID + h];
    v4f wd4[4][2];
#pragma unroll
    for (int c = 0; c < 4; ++c) {
        const v4f* wp = (const v4f*)(Wd + ((size_t)(p * DD + l * 4 + c)) * HID);
        wd4[c][0] = wp[0];
        wd4[c][1] = wp[1];
    }
    v4f bdv = *(const v4f*)(bd + p * DD + l * 4);

    const bool b5 = (l & 32) != 0;
    const bool b4 = (l & 16) != 0;
    const bool b3 = (l & 8)  != 0;

    // stripe is CONTIGUOUS in memory: rows ph*16 .. ph*16+15
    const float* xs = x   + (size_t)(sg * G) * IMG + ph * 2048;
    float*       os = out + (size_t)(sg * G) * IMG + ph * 2048;

    // prologue: stage sample 0
    {
        v4f xr = *(const v4f*)(xs + goff);
        *(v4f*)&Xb[0][lds_stage] = xr;
    }

#pragma unroll 1
    for (int s = 0; s < G; ++s) {
        // issue next sample's contiguous load early (hides HBM latency under compute)
        v4f xn;
        if (s + 1 < G)
            xn = *(const v4f*)(xs + (size_t)(s + 1) * IMG + goff);

        __syncthreads();   // B1: Xb[s&1] writes visible; prev iter's Ob reads done

        // ---- compute: wave w owns patch p; lane l owns d = 4l..4l+3 ----
        v4f xv = *(const v4f*)&Xb[s & 1][w * PSTRIDE + 4 * l];

        float z[HID];
#pragma unroll
        for (int h = 0; h < HID; ++h)
            z[h] = fmaf(we4[h].x, xv.x,
                   fmaf(we4[h].y, xv.y,
                   fmaf(we4[h].z, xv.z, we4[h].w * xv.w)));

        // reduce-scatter: mask32 keep 4, mask16 keep 2, mask8 keep 1
        float a[4];
#pragma unroll
        for (int c = 0; c < 4; ++c) {
            float send = b5 ? z[c]     : z[c + 4];
            float keep = b5 ? z[c + 4] : z[c];
            a[c] = keep + __shfl_xor(send, 32);
        }
        float bb[2];
#pragma unroll
        for (int c = 0; c < 2; ++c) {
            float send = b4 ? a[c]     : a[c + 2];
            float keep = b4 ? a[c + 2] : a[c];
            bb[c] = keep + __shfl_xor(send, 16);
        }
        float s1;
        {
            float send = b3 ? bb[0] : bb[1];
            float keep = b3 ? bb[1] : bb[0];
            s1 = keep + __shfl_xor(send, 8);
        }
#pragma unroll
        for (int m = 4; m >= 1; m >>= 1)
            s1 += __shfl_xor(s1, m);

        // broadcast (h lives at lane h*8) + decode + sigmoid
        float zf[HID];
#pragma unroll
        for (int h = 0; h < HID; ++h)
            zf[h] = rlane(s1, h * 8) + bev[h];

        v4f o;
#pragma unroll
        for (int c = 0; c < 4; ++c) {
            float acc = bdv[c];
#pragma unroll
            for (int h = 0; h < 4; ++h) acc = fmaf(wd4[c][0][h], zf[h], acc);
#pragma unroll
            for (int h = 0; h < 4; ++h) acc = fmaf(wd4[c][1][h], zf[h + 4], acc);
            o[c] = __builtin_amdgcn_rcpf(1.0f + __expf(-acc));
        }
        *(v4f*)&Ob[w * PSTRIDE + 4 * l] = o;

        // stage next sample's input (load already in flight)
        if (s + 1 < G)
            *(v4f*)&Xb[(s + 1) & 1][lds_stage] = xn;

        __syncthreads();   // B2: Ob writes visible; Xb[s+1] visible for next iter

        // contiguous store
        v4f ov = *(const v4f*)&Ob[lds_stage];
        *(v4f*)(os + (size_t)s * IMG + goff) = ov;
    }
}

extern "C" void kernel_launch(void* const* d_in, const int* in_sizes, int n_in,
                              void* d_out, int out_size, void* d_ws, size_t ws_size,
                              hipStream_t stream) {
    const float* x  = (const float*)d_in[0];
    const float* We = (const float*)d_in[1];
    const float* be = (const float*)d_in[2];
    const float* Wd = (const float*)d_in[3];
    const float* bd = (const float*)d_in[4];
    float* out = (float*)d_out;

    const int n_total = in_sizes[0] / IMG;          // 2048
    const int grid    = 16 * (n_total / G);         // 16 stripes * 128 groups = 2048
    lca_kernel<<<dim3(grid), dim3(512), 0, stream>>>(x, We, be, Wd, bd, out);
}

// Round 8
// 113.628 us; speedup vs baseline: 1.3536x; 1.1070x over previous
//
#include <hip/hip_runtime.h>

#define HH 256
#define WW 128
#define DD 256
#define HID 8
#define G 16              // samples per block
#define PSTRIDE 264       // padded per-patch stride in floats (256 + 8)
#define IMG (HH * WW)     // 32768 floats per sample

typedef float v4f __attribute__((ext_vector_type(4)));

__device__ __forceinline__ float rlane(float v, int l) {
    return __int_as_float(__builtin_amdgcn_readlane(__float_as_int(v), l));
}

__global__ __launch_bounds__(512, 4)
void lca_kernel(const float* __restrict__ x, const float* __restrict__ We,
                const float* __restrict__ be, const float* __restrict__ Wd,
                const float* __restrict__ bd, float* __restrict__ out) {
    __shared__ float Xb[2][8 * PSTRIDE];   // staged input, patch-major, dbuf
    __shared__ float Ob[2][8 * PSTRIDE];   // staged output, patch-major, dbuf

    const int bid = blockIdx.x;
    const int ph  = bid & 15;              // stripe (16 rows of the image)
    const int sg  = bid >> 4;              // sample group 0..127
    const int tid = threadIdx.x;
    const int w   = tid >> 6;              // wave index == patch pw within stripe
    const int l   = tid & 63;
    const int p   = ph * 8 + w;            // global patch id for this wave

    // stage mapping: thread t handles the contiguous float4 at stripe offset 4t
    const int r_t  = tid >> 5;
    const int pw_t = (tid >> 2) & 7;
    const int jj_t = (tid & 3) * 4;
    const int lds_stage = pw_t * PSTRIDE + r_t * 16 + jj_t;   // patch-major slot
    const int goff = tid * 4;                                  // contiguous offset

    // ---- weight preload (per wave, its patch) ----
    v4f we4[HID];
#pragma unroll
    for (int h = 0; h < HID; ++h)
        we4[h] = *(const v4f*)(We + ((size_t)(p * HID + h)) * DD + l * 4);
    float bev[HID];
#pragma unroll
    for (int h = 0; h < HID; ++h) bev[h] = be[p * HID + h];
    v4f wd4[4][2];
#pragma unroll
    for (int c = 0; c < 4; ++c) {
        const v4f* wp = (const v4f*)(Wd + ((size_t)(p * DD + l * 4 + c)) * HID);
        wd4[c][0] = wp[0];
        wd4[c][1] = wp[1];
    }
    v4f bdv = *(const v4f*)(bd + p * DD + l * 4);

    const bool b5 = (l & 32) != 0;
    const bool b4 = (l & 16) != 0;
    const bool b3 = (l & 8)  != 0;

    // stripe is CONTIGUOUS in memory: rows ph*16 .. ph*16+15
    const float* xs = x   + (size_t)(sg * G) * IMG + ph * 2048;
    float*       os = out + (size_t)(sg * G) * IMG + ph * 2048;

    // prologue: stage sample 0; hold sample 1 in regs
    {
        v4f x0 = *(const v4f*)(xs + goff);
        *(v4f*)&Xb[0][lds_stage] = x0;
    }
    v4f xn = *(const v4f*)(xs + IMG + goff);

#pragma unroll 1
    for (int s = 0; s < G; ++s) {
        // issue load for sample s+2 (stays in flight across the barrier)
        v4f xm;
        if (s + 2 < G)
            xm = *(const v4f*)(xs + (size_t)(s + 2) * IMG + goff);

        __syncthreads();   // the ONLY barrier per sample

        // ---- compute sample s: wave w owns patch p; lane l owns d = 4l..4l+3
        v4f xv = *(const v4f*)&Xb[s & 1][w * PSTRIDE + 4 * l];

        float z[HID];
#pragma unroll
        for (int h = 0; h < HID; ++h)
            z[h] = fmaf(we4[h].x, xv.x,
                   fmaf(we4[h].y, xv.y,
                   fmaf(we4[h].z, xv.z, we4[h].w * xv.w)));

        // reduce-scatter: mask32 keep 4, mask16 keep 2, mask8 keep 1
        float a[4];
#pragma unroll
        for (int c = 0; c < 4; ++c) {
            float send = b5 ? z[c]     : z[c + 4];
            float keep = b5 ? z[c + 4] : z[c];
            a[c] = keep + __shfl_xor(send, 32);
        }
        float bb[2];
#pragma unroll
        for (int c = 0; c < 2; ++c) {
            float send = b4 ? a[c]     : a[c + 2];
            float keep = b4 ? a[c + 2] : a[c];
            bb[c] = keep + __shfl_xor(send, 16);
        }
        float s1;
        {
            float send = b3 ? bb[0] : bb[1];
            float keep = b3 ? bb[1] : bb[0];
            s1 = keep + __shfl_xor(send, 8);
        }
#pragma unroll
        for (int m = 4; m >= 1; m >>= 1)
            s1 += __shfl_xor(s1, m);

        // broadcast (h lives at lane h*8) + decode + sigmoid
        float zf[HID];
#pragma unroll
        for (int h = 0; h < HID; ++h)
            zf[h] = rlane(s1, h * 8) + bev[h];

        v4f o;
#pragma unroll
        for (int c = 0; c < 4; ++c) {
            float acc = bdv[c];
#pragma unroll
            for (int h = 0; h < 4; ++h) acc = fmaf(wd4[c][0][h], zf[h], acc);
#pragma unroll
            for (int h = 0; h < 4; ++h) acc = fmaf(wd4[c][1][h], zf[h + 4], acc);
            o[c] = __builtin_amdgcn_rcpf(1.0f + __expf(-acc));
        }
        *(v4f*)&Ob[s & 1][w * PSTRIDE + 4 * l] = o;

        // stage next sample's input (reg-held, load long since issued)
        if (s + 1 < G)
            *(v4f*)&Xb[(s + 1) & 1][lds_stage] = xn;

        // store PREVIOUS sample's output (written before this iter's barrier)
        if (s > 0) {
            v4f ov = *(const v4f*)&Ob[(s - 1) & 1][lds_stage];
            __builtin_nontemporal_store(ov, (v4f*)(os + (size_t)(s - 1) * IMG + goff));
        }
        xn = xm;
    }

    // epilogue: store the last sample
    __syncthreads();
    {
        v4f ov = *(const v4f*)&Ob[(G - 1) & 1][lds_stage];
        __builtin_nontemporal_store(ov, (v4f*)(os + (size_t)(G - 1) * IMG + goff));
    }
}

extern "C" void kernel_launch(void* const* d_in, const int* in_sizes, int n_in,
                              void* d_out, int out_size, void* d_ws, size_t ws_size,
                              hipStream_t stream) {
    const float* x  = (const float*)d_in[0];
    const float* We = (const float*)d_in[1];
    const float* be = (const float*)d_in[2];
    const float* Wd = (const float*)d_in[3];
    const float* bd = (const float*)d_in[4];
    float* out = (float*)d_out;

    const int n_total = in_sizes[0] / IMG;          // 2048
    const int grid    = 16 * (n_total / G);         // 16 stripes * 128 groups = 2048
    lca_kernel<<<dim3(grid), dim3(512), 0, stream>>>(x, We, be, Wd, bd, out);
}